// Round 2
// baseline (467.033 us; speedup 1.0000x reference)
//
#include <hip/hip_runtime.h>
#include <math.h>

#define KF 8
#define LL 8
#define TT (1 << 18)
#define HID 64
#define INF 16          // L*F = MLP input dim
// LDS strides (floats). Bank = float_index % 32. Need k*stride % 32 to spread:
//   1064 % 32 = 8  -> clusters land on bank offsets {0,8,16,24} -> 2-way max (free, m136)
//   1064 % 4  = 0  -> float4-aligned
#define W1S 1064
#define BS  72          // 72 % 32 = 8, 72 % 4 = 0
#define BT  256         // block threads
#define CCH 256         // chunk grid per (cluster,level)

// ---------- shared helpers ----------

__device__ __forceinline__ int cluster_assign(float px, float py, float pz,
                                              const float* __restrict__ c) {
    int a = 0; float best = 1e30f;
    #pragma unroll
    for (int k = 0; k < KF; ++k) {
        float dx = px - c[k * 3 + 0];
        float dy = py - c[k * 3 + 1];
        float dz = pz - c[k * 3 + 2];
        float d2 = fmaf(dx, dx, fmaf(dy, dy, dz * dz));
        bool lt = d2 < best;
        a = lt ? k : a;
        best = lt ? d2 : best;
    }
    return a;
}

__device__ __forceinline__ float2 gather_level(const float2* __restrict__ tl,
                                               float px, float py, float pz, int l) {
    const float res = (float)(16 << l);
    const float sx = px * res, sy = py * res, sz = pz * res;
    const float fx = floorf(sx), fy = floorf(sy), fz = floorf(sz);
    const float wx = sx - fx, wy = sy - fy, wz = sz - fz;
    const unsigned ix = (unsigned)(int)fx;
    const unsigned iy = (unsigned)(int)fy;
    const unsigned iz = (unsigned)(int)fz;

    const unsigned hx0 = ix;
    const unsigned hx1 = ix + 1u;
    const unsigned hy0 = iy * 2654435761u;
    const unsigned hy1 = (iy + 1u) * 2654435761u;
    const unsigned hz0 = iz * 805459861u;
    const unsigned hz1 = (iz + 1u) * 805459861u;
    const unsigned M = TT - 1;

    const float2 c000 = tl[(hx0 ^ hy0 ^ hz0) & M];
    const float2 c001 = tl[(hx0 ^ hy0 ^ hz1) & M];
    const float2 c010 = tl[(hx0 ^ hy1 ^ hz0) & M];
    const float2 c011 = tl[(hx0 ^ hy1 ^ hz1) & M];
    const float2 c100 = tl[(hx1 ^ hy0 ^ hz0) & M];
    const float2 c101 = tl[(hx1 ^ hy0 ^ hz1) & M];
    const float2 c110 = tl[(hx1 ^ hy1 ^ hz0) & M];
    const float2 c111 = tl[(hx1 ^ hy1 ^ hz1) & M];

    const float ux = 1.f - wx, uy = 1.f - wy, uz = 1.f - wz;
    const float w000 = ux * uy * uz, w001 = ux * uy * wz;
    const float w010 = ux * wy * uz, w011 = ux * wy * wz;
    const float w100 = wx * uy * uz, w101 = wx * uy * wz;
    const float w110 = wx * wy * uz, w111 = wx * wy * wz;

    float ex = c000.x * w000 + c001.x * w001 + c010.x * w010 + c011.x * w011
             + c100.x * w100 + c101.x * w101 + c110.x * w110 + c111.x * w111;
    float ey = c000.y * w000 + c001.y * w001 + c010.y * w010 + c011.y * w011
             + c100.y * w100 + c101.y * w101 + c110.y * w110 + c111.y * w111;
    return make_float2(ex, ey);
}

// ---------- phase S: counting sort by cluster ----------

__global__ void k_init(int* p) {
    if (threadIdx.x < 16) p[threadIdx.x] = 0;  // counts[8] + cursor slack
}

__global__ __launch_bounds__(BT) void k_count(const float* __restrict__ pos,
                                              const float* __restrict__ cent,
                                              int* __restrict__ counts, int n) {
    __shared__ int h[KF];
    if (threadIdx.x < KF) h[threadIdx.x] = 0;
    __syncthreads();
    const int gid = blockIdx.x * BT + threadIdx.x;
    if (gid < n) {
        float px = pos[gid * 3], py = pos[gid * 3 + 1], pz = pos[gid * 3 + 2];
        atomicAdd(&h[cluster_assign(px, py, pz, cent)], 1);
    }
    __syncthreads();
    if (threadIdx.x < KF && h[threadIdx.x] > 0)
        atomicAdd(&counts[threadIdx.x], h[threadIdx.x]);
}

__global__ void k_scan(const int* __restrict__ counts,
                       int* __restrict__ base, int* __restrict__ cursor) {
    if (threadIdx.x == 0) {
        int acc = 0;
        for (int k = 0; k < KF; ++k) { base[k] = acc; cursor[k] = acc; acc += counts[k]; }
    }
}

__global__ __launch_bounds__(BT) void k_scatter(const float* __restrict__ pos,
                                                const float* __restrict__ cent,
                                                int* __restrict__ cursor,
                                                float4* __restrict__ sorted, int n) {
    __shared__ int h[KF];
    __shared__ int gb[KF];
    if (threadIdx.x < KF) h[threadIdx.x] = 0;
    __syncthreads();
    const int gid = blockIdx.x * BT + threadIdx.x;
    int a = 0, r = 0;
    float px = 0.f, py = 0.f, pz = 0.f;
    if (gid < n) {
        px = pos[gid * 3]; py = pos[gid * 3 + 1]; pz = pos[gid * 3 + 2];
        a = cluster_assign(px, py, pz, cent);
        r = atomicAdd(&h[a], 1);
    }
    __syncthreads();
    if (threadIdx.x < KF && h[threadIdx.x] > 0)
        gb[threadIdx.x] = atomicAdd(&cursor[threadIdx.x], h[threadIdx.x]);
    __syncthreads();
    if (gid < n)
        sorted[gb[a] + r] = make_float4(px, py, pz, __int_as_float(gid));
}

// ---------- phase B: (cluster,level)-tiled gather ----------
// grid = LL * CCH * KF blocks; blockIdx = (l*CCH + c)*KF + k  ->  k = b%8 tracks XCD,
// l is slowest so each XCD sees one cluster's one 2MiB table at a time (L2-resident).

__global__ __launch_bounds__(BT, 8) void k_gather(const float2* __restrict__ tables,
                                                  const float4* __restrict__ sorted,
                                                  const int* __restrict__ base,
                                                  const int* __restrict__ counts,
                                                  float2* __restrict__ enc, int n) {
    const int b = blockIdx.x;
    const int k = b & 7;
    const int t = b >> 3;
    const int c = t & (CCH - 1);
    const int l = t >> 8;           // CCH == 256
    const int start = base[k];
    const int cnt = counts[k];
    const float2* __restrict__ tl = tables + ((size_t)k * LL + l) * TT;
    float2* __restrict__ encl = enc + (size_t)l * n;

    for (int i = c * BT + threadIdx.x; i < cnt; i += CCH * BT) {
        const float4 p = sorted[start + i];
        encl[start + i] = gather_level(tl, p.x, p.y, p.z, l);
    }
}

// ---------- phase C: MLP over sorted points ----------

__global__ __launch_bounds__(BT) void k_mlp(const float4* __restrict__ sorted,
                                            const float2* __restrict__ enc,
                                            const float* __restrict__ cent,
                                            const float* __restrict__ W1,
                                            const float* __restrict__ b1,
                                            const float* __restrict__ W2,
                                            const float* __restrict__ b2,
                                            float* __restrict__ out, int n) {
    __shared__ float sW1[KF * W1S];
    __shared__ float sB1[KF * BS];
    __shared__ float sW2[KF * BS];
    __shared__ float sB2[KF];
    __shared__ float sC[KF * 3];

    const int tid = threadIdx.x;
    for (int idx = tid; idx < KF * INF * HID; idx += BT) {
        int k = idx >> 10;
        int r = idx & 1023;
        sW1[k * W1S + r] = W1[idx];
    }
    for (int idx = tid; idx < KF * HID; idx += BT) {
        int k = idx >> 6;
        int r = idx & 63;
        sB1[k * BS + r] = b1[idx];
        sW2[k * BS + r] = W2[idx];
    }
    if (tid < KF) sB2[tid] = b2[tid];
    if (tid < KF * 3) sC[tid] = cent[tid];
    __syncthreads();

    const int gid = blockIdx.x * BT + tid;
    if (gid >= n) return;

    const float4 p = sorted[gid];
    const int assign = cluster_assign(p.x, p.y, p.z, sC);  // bit-identical to sort phase

    float encr[INF];
    #pragma unroll
    for (int l = 0; l < LL; ++l) {
        const float2 e = enc[(size_t)l * n + gid];   // coalesced
        encr[l * 2 + 0] = e.x;
        encr[l * 2 + 1] = e.y;
    }

    const float4* __restrict__ w1k = (const float4*)(sW1 + assign * W1S);
    const float4* __restrict__ b1k = (const float4*)(sB1 + assign * BS);
    const float4* __restrict__ w2k = (const float4*)(sW2 + assign * BS);

    float outv = sB2[assign];
    #pragma unroll
    for (int j4 = 0; j4 < HID / 4; ++j4) {
        float4 a = b1k[j4];
        #pragma unroll
        for (int i = 0; i < INF; ++i) {
            const float4 w = w1k[i * (HID / 4) + j4];
            const float e = encr[i];
            a.x = fmaf(e, w.x, a.x);
            a.y = fmaf(e, w.y, a.y);
            a.z = fmaf(e, w.z, a.z);
            a.w = fmaf(e, w.w, a.w);
        }
        a.x = fmaxf(a.x, 0.f); a.y = fmaxf(a.y, 0.f);
        a.z = fmaxf(a.z, 0.f); a.w = fmaxf(a.w, 0.f);
        const float4 w2v = w2k[j4];
        outv = fmaf(a.x, w2v.x, outv);
        outv = fmaf(a.y, w2v.y, outv);
        outv = fmaf(a.z, w2v.z, outv);
        outv = fmaf(a.w, w2v.w, outv);
    }

    out[__float_as_int(p.w)] = expf(outv);
}

// ---------- fallback fused kernel (if ws too small) ----------

__global__ __launch_bounds__(BT) void k_fused(const float* __restrict__ positions,
                                              const float* __restrict__ centroids,
                                              const float* __restrict__ tables,
                                              const float* __restrict__ W1,
                                              const float* __restrict__ b1,
                                              const float* __restrict__ W2,
                                              const float* __restrict__ b2,
                                              float* __restrict__ out, int npts) {
    __shared__ float sW1[KF * W1S];
    __shared__ float sB1[KF * BS];
    __shared__ float sW2[KF * BS];
    __shared__ float sB2[KF];
    __shared__ float sC[KF * 3];

    const int tid = threadIdx.x;
    for (int idx = tid; idx < KF * INF * HID; idx += BT) {
        int k = idx >> 10; int r = idx & 1023;
        sW1[k * W1S + r] = W1[idx];
    }
    for (int idx = tid; idx < KF * HID; idx += BT) {
        int k = idx >> 6; int r = idx & 63;
        sB1[k * BS + r] = b1[idx];
        sW2[k * BS + r] = W2[idx];
    }
    if (tid < KF) sB2[tid] = b2[tid];
    if (tid < KF * 3) sC[tid] = centroids[tid];
    __syncthreads();

    const int gid = blockIdx.x * BT + tid;
    if (gid >= npts) return;

    const float px = positions[gid * 3 + 0];
    const float py = positions[gid * 3 + 1];
    const float pz = positions[gid * 3 + 2];
    const int assign = cluster_assign(px, py, pz, sC);

    float encr[INF];
    const float2* __restrict__ tab =
        (const float2*)tables + (size_t)assign * (LL * (size_t)TT);
    #pragma unroll
    for (int l = 0; l < LL; ++l) {
        float2 e = gather_level(tab + (size_t)l * TT, px, py, pz, l);
        encr[l * 2 + 0] = e.x;
        encr[l * 2 + 1] = e.y;
    }

    const float4* __restrict__ w1k = (const float4*)(sW1 + assign * W1S);
    const float4* __restrict__ b1k = (const float4*)(sB1 + assign * BS);
    const float4* __restrict__ w2k = (const float4*)(sW2 + assign * BS);

    float outv = sB2[assign];
    #pragma unroll
    for (int j4 = 0; j4 < HID / 4; ++j4) {
        float4 a = b1k[j4];
        #pragma unroll
        for (int i = 0; i < INF; ++i) {
            const float4 w = w1k[i * (HID / 4) + j4];
            const float e = encr[i];
            a.x = fmaf(e, w.x, a.x);
            a.y = fmaf(e, w.y, a.y);
            a.z = fmaf(e, w.z, a.z);
            a.w = fmaf(e, w.w, a.w);
        }
        a.x = fmaxf(a.x, 0.f); a.y = fmaxf(a.y, 0.f);
        a.z = fmaxf(a.z, 0.f); a.w = fmaxf(a.w, 0.f);
        const float4 w2v = w2k[j4];
        outv = fmaf(a.x, w2v.x, outv);
        outv = fmaf(a.y, w2v.y, outv);
        outv = fmaf(a.z, w2v.z, outv);
        outv = fmaf(a.w, w2v.w, outv);
    }
    out[gid] = expf(outv);
}

// ---------- launch ----------

extern "C" void kernel_launch(void* const* d_in, const int* in_sizes, int n_in,
                              void* d_out, int out_size, void* d_ws, size_t ws_size,
                              hipStream_t stream) {
    const float* positions = (const float*)d_in[0];
    const float* centroids = (const float*)d_in[1];
    const float* tables    = (const float*)d_in[2];
    const float* W1        = (const float*)d_in[3];
    const float* b1        = (const float*)d_in[4];
    const float* W2        = (const float*)d_in[5];
    const float* b2        = (const float*)d_in[6];
    float* out = (float*)d_out;

    const int n = in_sizes[0] / 3;
    const int nblk = (n + BT - 1) / BT;

    // ws layout: [0:32) counts, [64:96) base, [128:160) cursor,
    //            [256, 256+16n) sorted float4, then LL*n float2 enc
    const size_t need = 256 + (size_t)n * 16 + (size_t)LL * n * 8;

    if (ws_size >= need) {
        char* ws = (char*)d_ws;
        int* counts   = (int*)(ws + 0);
        int* base     = (int*)(ws + 64);
        int* cursor   = (int*)(ws + 128);
        float4* sorted = (float4*)(ws + 256);
        float2* enc    = (float2*)(ws + 256 + (size_t)n * 16);

        k_init<<<1, 64, 0, stream>>>(counts);
        k_count<<<nblk, BT, 0, stream>>>(positions, centroids, counts, n);
        k_scan<<<1, 64, 0, stream>>>(counts, base, cursor);
        k_scatter<<<nblk, BT, 0, stream>>>(positions, centroids, cursor, sorted, n);
        k_gather<<<LL * CCH * KF, BT, 0, stream>>>((const float2*)tables, sorted,
                                                   base, counts, enc, n);
        k_mlp<<<nblk, BT, 0, stream>>>(sorted, enc, centroids,
                                       W1, b1, W2, b2, out, n);
    } else {
        k_fused<<<nblk, BT, 0, stream>>>(positions, centroids, tables,
                                         W1, b1, W2, b2, out, n);
    }
}

// Round 3
// 441.342 us; speedup vs baseline: 1.0582x; 1.0582x over previous
//
#include <hip/hip_runtime.h>
#include <math.h>

#define KF 8
#define LL 8
#define TT (1 << 18)
#define HID 64
#define INF 16          // L*F = MLP input dim
// LDS strides (floats). Bank = float_index % 32.
//   1064 % 32 = 8 -> clusters at bank offsets {0,8,16,24} -> 2-way max (free, m136)
#define W1S 1064
#define BS  72          // 72 % 32 = 8, 72 % 4 = 0
#define BT  256

// ---------- helpers ----------

__device__ __forceinline__ int cluster_assign(float px, float py, float pz,
                                              const float* __restrict__ c) {
    int a = 0; float best = 1e30f;
    #pragma unroll
    for (int k = 0; k < KF; ++k) {
        float dx = px - c[k * 3 + 0];
        float dy = py - c[k * 3 + 1];
        float dz = pz - c[k * 3 + 2];
        float d2 = fmaf(dx, dx, fmaf(dy, dy, dz * dz));
        bool lt = d2 < best;
        a = lt ? k : a;
        best = lt ? d2 : best;
    }
    return a;
}

// x-paired gather: x-hash prime is 1, so for even ix the (x0,x1) corner pair
// occupies adjacent float2 slots -> one float4 load. Odd-ix lanes do a masked
// second load. Lane-requests per point-level: 8 -> ~6.
__device__ __forceinline__ float2 gather_level(const float2* __restrict__ tl,
                                               float px, float py, float pz, int l) {
    const float res = (float)(16 << l);
    const float sx = px * res, sy = py * res, sz = pz * res;
    const float fx = floorf(sx), fy = floorf(sy), fz = floorf(sz);
    const float wx = sx - fx, wy = sy - fy, wz = sz - fz;
    const unsigned ix = (unsigned)(int)fx;
    const unsigned iy = (unsigned)(int)fy;
    const unsigned iz = (unsigned)(int)fz;
    const unsigned M = TT - 1;

    const unsigned hy0 = iy * 2654435761u;
    const unsigned hy1 = (iy + 1u) * 2654435761u;
    const unsigned hz0 = iz * 805459861u;
    const unsigned hz1 = (iz + 1u) * 805459861u;

    const unsigned q00 = hy0 ^ hz0, q01 = hy0 ^ hz1;
    const unsigned q10 = hy1 ^ hz0, q11 = hy1 ^ hz1;

    const unsigned i00 = (ix ^ q00) & M;
    const unsigned i01 = (ix ^ q01) & M;
    const unsigned i10 = (ix ^ q10) & M;
    const unsigned i11 = (ix ^ q11) & M;

    const float4* __restrict__ tl4 = (const float4*)tl;
    const float4 f00 = tl4[i00 >> 1];
    const float4 f01 = tl4[i01 >> 1];
    const float4 f10 = tl4[i10 >> 1];
    const float4 f11 = tl4[i11 >> 1];

    const bool odd = (ix & 1u) != 0u;
    const unsigned jx = ix + 1u;
    float2 g00, g01, g10, g11;
    if (odd) {   // exec-masked loads, ~half the lanes
        g00 = tl[(jx ^ q00) & M];
        g01 = tl[(jx ^ q01) & M];
        g10 = tl[(jx ^ q10) & M];
        g11 = tl[(jx ^ q11) & M];
    }

    const float2 lo00 = make_float2(f00.x, f00.y), hi00 = make_float2(f00.z, f00.w);
    const float2 lo01 = make_float2(f01.x, f01.y), hi01 = make_float2(f01.z, f01.w);
    const float2 lo10 = make_float2(f10.x, f10.y), hi10 = make_float2(f10.z, f10.w);
    const float2 lo11 = make_float2(f11.x, f11.y), hi11 = make_float2(f11.z, f11.w);

    const float2 c000 = (i00 & 1) ? hi00 : lo00;
    const float2 c001 = (i01 & 1) ? hi01 : lo01;
    const float2 c010 = (i10 & 1) ? hi10 : lo10;
    const float2 c011 = (i11 & 1) ? hi11 : lo11;
    const float2 c100 = odd ? g00 : ((i00 & 1) ? lo00 : hi00);
    const float2 c101 = odd ? g01 : ((i01 & 1) ? lo01 : hi01);
    const float2 c110 = odd ? g10 : ((i10 & 1) ? lo10 : hi10);
    const float2 c111 = odd ? g11 : ((i11 & 1) ? lo11 : hi11);

    const float ux = 1.f - wx, uy = 1.f - wy, uz = 1.f - wz;
    const float w000 = ux * uy * uz, w001 = ux * uy * wz;
    const float w010 = ux * wy * uz, w011 = ux * wy * wz;
    const float w100 = wx * uy * uz, w101 = wx * uy * wz;
    const float w110 = wx * wy * uz, w111 = wx * wy * wz;

    float ex = c000.x * w000 + c001.x * w001 + c010.x * w010 + c011.x * w011
             + c100.x * w100 + c101.x * w101 + c110.x * w110 + c111.x * w111;
    float ey = c000.y * w000 + c001.y * w001 + c010.y * w010 + c011.y * w011
             + c100.y * w100 + c101.y * w101 + c110.y * w110 + c111.y * w111;
    return make_float2(ex, ey);
}

// ---------- counting sort by cluster ----------

__global__ void k_init(int* p) {
    if (threadIdx.x < 16) p[threadIdx.x] = 0;
}

__global__ __launch_bounds__(BT) void k_count(const float* __restrict__ pos,
                                              const float* __restrict__ cent,
                                              int* __restrict__ counts, int n) {
    __shared__ int h[KF];
    if (threadIdx.x < KF) h[threadIdx.x] = 0;
    __syncthreads();
    const int gid = blockIdx.x * BT + threadIdx.x;
    if (gid < n) {
        float px = pos[gid * 3], py = pos[gid * 3 + 1], pz = pos[gid * 3 + 2];
        atomicAdd(&h[cluster_assign(px, py, pz, cent)], 1);
    }
    __syncthreads();
    if (threadIdx.x < KF && h[threadIdx.x] > 0)
        atomicAdd(&counts[threadIdx.x], h[threadIdx.x]);
}

__global__ void k_scan(const int* __restrict__ counts,
                       int* __restrict__ base, int* __restrict__ cursor) {
    if (threadIdx.x == 0) {
        int acc = 0;
        for (int k = 0; k < KF; ++k) { base[k] = acc; cursor[k] = acc; acc += counts[k]; }
    }
}

__global__ __launch_bounds__(BT) void k_scatter(const float* __restrict__ pos,
                                                const float* __restrict__ cent,
                                                int* __restrict__ cursor,
                                                float4* __restrict__ sorted, int n) {
    __shared__ int h[KF];
    __shared__ int gb[KF];
    if (threadIdx.x < KF) h[threadIdx.x] = 0;
    __syncthreads();
    const int gid = blockIdx.x * BT + threadIdx.x;
    int a = 0, r = 0;
    float px = 0.f, py = 0.f, pz = 0.f;
    if (gid < n) {
        px = pos[gid * 3]; py = pos[gid * 3 + 1]; pz = pos[gid * 3 + 2];
        a = cluster_assign(px, py, pz, cent);
        r = atomicAdd(&h[a], 1);
    }
    __syncthreads();
    if (threadIdx.x < KF && h[threadIdx.x] > 0)
        gb[threadIdx.x] = atomicAdd(&cursor[threadIdx.x], h[threadIdx.x]);
    __syncthreads();
    if (gid < n)
        sorted[gb[a] + r] = make_float4(px, py, pz, __int_as_float(gid));
}

// ---------- fused gather+MLP over sorted points, 2 points/thread ----------

__global__ __launch_bounds__(BT) void k_main(const float4* __restrict__ sorted,
                                             const float2* __restrict__ tables,
                                             const float* __restrict__ cent,
                                             const float* __restrict__ W1,
                                             const float* __restrict__ b1,
                                             const float* __restrict__ W2,
                                             const float* __restrict__ b2,
                                             float* __restrict__ out, int n) {
    __shared__ float sW1[KF * W1S];
    __shared__ float sB1[KF * BS];
    __shared__ float sW2[KF * BS];
    __shared__ float sB2[KF];
    __shared__ float sC[KF * 3];

    const int tid = threadIdx.x;
    {   // float4 weight staging
        const float4* __restrict__ W14 = (const float4*)W1;
        for (int idx = tid; idx < KF * INF * HID / 4; idx += BT) {
            int k = idx >> 8;           // / 256 float4s per cluster
            int r = idx & 255;
            *(float4*)(sW1 + k * W1S + r * 4) = W14[idx];
        }
    }
    for (int idx = tid; idx < KF * HID; idx += BT) {
        int k = idx >> 6; int r = idx & 63;
        sB1[k * BS + r] = b1[idx];
        sW2[k * BS + r] = W2[idx];
    }
    if (tid < KF) sB2[tid] = b2[tid];
    if (tid < KF * 3) sC[tid] = cent[tid];
    __syncthreads();

    const int i0 = blockIdx.x * (2 * BT) + tid;
    if (i0 >= n) return;
    const int i1 = i0 + BT;
    const bool v1 = i1 < n;

    const float4 p0 = sorted[i0];
    const float4 p1 = sorted[v1 ? i1 : i0];

    const int a0 = cluster_assign(p0.x, p0.y, p0.z, sC);
    const int a1 = cluster_assign(p1.x, p1.y, p1.z, sC);

    const float2* __restrict__ tab0 = tables + (size_t)a0 * (LL * (size_t)TT);
    const float2* __restrict__ tab1 = tables + (size_t)a1 * (LL * (size_t)TT);

    float e0[INF], e1[INF];
    #pragma unroll
    for (int l = 0; l < LL; ++l) {
        const float2 r0 = gather_level(tab0 + (size_t)l * TT, p0.x, p0.y, p0.z, l);
        const float2 r1 = gather_level(tab1 + (size_t)l * TT, p1.x, p1.y, p1.z, l);
        e0[l * 2 + 0] = r0.x; e0[l * 2 + 1] = r0.y;
        e1[l * 2 + 0] = r1.x; e1[l * 2 + 1] = r1.y;
    }

    const float4* __restrict__ w1k0 = (const float4*)(sW1 + a0 * W1S);
    const float4* __restrict__ b1k0 = (const float4*)(sB1 + a0 * BS);
    const float4* __restrict__ w2k0 = (const float4*)(sW2 + a0 * BS);

    float o0 = sB2[a0], o1 = sB2[a1];

    if (a0 == a1) {   // common case: wave-coherent, shared weight reads
        #pragma unroll
        for (int j4 = 0; j4 < HID / 4; ++j4) {
            float4 acc0 = b1k0[j4];
            float4 acc1 = acc0;
            #pragma unroll
            for (int i = 0; i < INF; ++i) {
                const float4 w = w1k0[i * (HID / 4) + j4];
                const float x0 = e0[i], x1 = e1[i];
                acc0.x = fmaf(x0, w.x, acc0.x); acc1.x = fmaf(x1, w.x, acc1.x);
                acc0.y = fmaf(x0, w.y, acc0.y); acc1.y = fmaf(x1, w.y, acc1.y);
                acc0.z = fmaf(x0, w.z, acc0.z); acc1.z = fmaf(x1, w.z, acc1.z);
                acc0.w = fmaf(x0, w.w, acc0.w); acc1.w = fmaf(x1, w.w, acc1.w);
            }
            acc0.x = fmaxf(acc0.x, 0.f); acc0.y = fmaxf(acc0.y, 0.f);
            acc0.z = fmaxf(acc0.z, 0.f); acc0.w = fmaxf(acc0.w, 0.f);
            acc1.x = fmaxf(acc1.x, 0.f); acc1.y = fmaxf(acc1.y, 0.f);
            acc1.z = fmaxf(acc1.z, 0.f); acc1.w = fmaxf(acc1.w, 0.f);
            const float4 w2v = w2k0[j4];
            o0 = fmaf(acc0.x, w2v.x, o0); o1 = fmaf(acc1.x, w2v.x, o1);
            o0 = fmaf(acc0.y, w2v.y, o0); o1 = fmaf(acc1.y, w2v.y, o1);
            o0 = fmaf(acc0.z, w2v.z, o0); o1 = fmaf(acc1.z, w2v.z, o1);
            o0 = fmaf(acc0.w, w2v.w, o0); o1 = fmaf(acc1.w, w2v.w, o1);
        }
    } else {          // straddle block: two weight streams
        const float4* __restrict__ w1k1 = (const float4*)(sW1 + a1 * W1S);
        const float4* __restrict__ b1k1 = (const float4*)(sB1 + a1 * BS);
        const float4* __restrict__ w2k1 = (const float4*)(sW2 + a1 * BS);
        #pragma unroll
        for (int j4 = 0; j4 < HID / 4; ++j4) {
            float4 acc0 = b1k0[j4];
            float4 acc1 = b1k1[j4];
            #pragma unroll
            for (int i = 0; i < INF; ++i) {
                const float4 wa = w1k0[i * (HID / 4) + j4];
                const float4 wb = w1k1[i * (HID / 4) + j4];
                const float x0 = e0[i], x1 = e1[i];
                acc0.x = fmaf(x0, wa.x, acc0.x); acc1.x = fmaf(x1, wb.x, acc1.x);
                acc0.y = fmaf(x0, wa.y, acc0.y); acc1.y = fmaf(x1, wb.y, acc1.y);
                acc0.z = fmaf(x0, wa.z, acc0.z); acc1.z = fmaf(x1, wb.z, acc1.z);
                acc0.w = fmaf(x0, wa.w, acc0.w); acc1.w = fmaf(x1, wb.w, acc1.w);
            }
            acc0.x = fmaxf(acc0.x, 0.f); acc0.y = fmaxf(acc0.y, 0.f);
            acc0.z = fmaxf(acc0.z, 0.f); acc0.w = fmaxf(acc0.w, 0.f);
            acc1.x = fmaxf(acc1.x, 0.f); acc1.y = fmaxf(acc1.y, 0.f);
            acc1.z = fmaxf(acc1.z, 0.f); acc1.w = fmaxf(acc1.w, 0.f);
            const float4 w2a = w2k0[j4];
            const float4 w2b = w2k1[j4];
            o0 = fmaf(acc0.x, w2a.x, o0); o1 = fmaf(acc1.x, w2b.x, o1);
            o0 = fmaf(acc0.y, w2a.y, o0); o1 = fmaf(acc1.y, w2b.y, o1);
            o0 = fmaf(acc0.z, w2a.z, o0); o1 = fmaf(acc1.z, w2b.z, o1);
            o0 = fmaf(acc0.w, w2a.w, o0); o1 = fmaf(acc1.w, w2b.w, o1);
        }
    }

    out[__float_as_int(p0.w)] = expf(o0);
    if (v1) out[__float_as_int(p1.w)] = expf(o1);
}

// ---------- fallback: unsorted fused (small ws) ----------

__global__ __launch_bounds__(BT) void k_fused(const float* __restrict__ positions,
                                              const float* __restrict__ centroids,
                                              const float* __restrict__ tables,
                                              const float* __restrict__ W1,
                                              const float* __restrict__ b1,
                                              const float* __restrict__ W2,
                                              const float* __restrict__ b2,
                                              float* __restrict__ out, int npts) {
    __shared__ float sW1[KF * W1S];
    __shared__ float sB1[KF * BS];
    __shared__ float sW2[KF * BS];
    __shared__ float sB2[KF];
    __shared__ float sC[KF * 3];

    const int tid = threadIdx.x;
    for (int idx = tid; idx < KF * INF * HID; idx += BT) {
        int k = idx >> 10; int r = idx & 1023;
        sW1[k * W1S + r] = W1[idx];
    }
    for (int idx = tid; idx < KF * HID; idx += BT) {
        int k = idx >> 6; int r = idx & 63;
        sB1[k * BS + r] = b1[idx];
        sW2[k * BS + r] = W2[idx];
    }
    if (tid < KF) sB2[tid] = b2[tid];
    if (tid < KF * 3) sC[tid] = centroids[tid];
    __syncthreads();

    const int gid = blockIdx.x * BT + tid;
    if (gid >= npts) return;

    const float px = positions[gid * 3 + 0];
    const float py = positions[gid * 3 + 1];
    const float pz = positions[gid * 3 + 2];
    const int assign = cluster_assign(px, py, pz, sC);

    float encr[INF];
    const float2* __restrict__ tab =
        (const float2*)tables + (size_t)assign * (LL * (size_t)TT);
    #pragma unroll
    for (int l = 0; l < LL; ++l) {
        float2 e = gather_level(tab + (size_t)l * TT, px, py, pz, l);
        encr[l * 2 + 0] = e.x;
        encr[l * 2 + 1] = e.y;
    }

    const float4* __restrict__ w1k = (const float4*)(sW1 + assign * W1S);
    const float4* __restrict__ b1k = (const float4*)(sB1 + assign * BS);
    const float4* __restrict__ w2k = (const float4*)(sW2 + assign * BS);

    float outv = sB2[assign];
    #pragma unroll
    for (int j4 = 0; j4 < HID / 4; ++j4) {
        float4 a = b1k[j4];
        #pragma unroll
        for (int i = 0; i < INF; ++i) {
            const float4 w = w1k[i * (HID / 4) + j4];
            const float e = encr[i];
            a.x = fmaf(e, w.x, a.x);
            a.y = fmaf(e, w.y, a.y);
            a.z = fmaf(e, w.z, a.z);
            a.w = fmaf(e, w.w, a.w);
        }
        a.x = fmaxf(a.x, 0.f); a.y = fmaxf(a.y, 0.f);
        a.z = fmaxf(a.z, 0.f); a.w = fmaxf(a.w, 0.f);
        const float4 w2v = w2k[j4];
        outv = fmaf(a.x, w2v.x, outv);
        outv = fmaf(a.y, w2v.y, outv);
        outv = fmaf(a.z, w2v.z, outv);
        outv = fmaf(a.w, w2v.w, outv);
    }
    out[gid] = expf(outv);
}

// ---------- launch ----------

extern "C" void kernel_launch(void* const* d_in, const int* in_sizes, int n_in,
                              void* d_out, int out_size, void* d_ws, size_t ws_size,
                              hipStream_t stream) {
    const float* positions = (const float*)d_in[0];
    const float* centroids = (const float*)d_in[1];
    const float* tables    = (const float*)d_in[2];
    const float* W1        = (const float*)d_in[3];
    const float* b1        = (const float*)d_in[4];
    const float* W2        = (const float*)d_in[5];
    const float* b2        = (const float*)d_in[6];
    float* out = (float*)d_out;

    const int n = in_sizes[0] / 3;
    const int nblk = (n + BT - 1) / BT;
    const size_t need = 256 + (size_t)n * 16;

    if (ws_size >= need) {
        char* ws = (char*)d_ws;
        int* counts    = (int*)(ws + 0);
        int* base      = (int*)(ws + 64);
        int* cursor    = (int*)(ws + 128);
        float4* sorted = (float4*)(ws + 256);

        k_init<<<1, 64, 0, stream>>>(counts);
        k_count<<<nblk, BT, 0, stream>>>(positions, centroids, counts, n);
        k_scan<<<1, 64, 0, stream>>>(counts, base, cursor);
        k_scatter<<<nblk, BT, 0, stream>>>(positions, centroids, cursor, sorted, n);
        const int mblk = (n + 2 * BT - 1) / (2 * BT);
        k_main<<<mblk, BT, 0, stream>>>(sorted, (const float2*)tables, centroids,
                                        W1, b1, W2, b2, out, n);
    } else {
        k_fused<<<nblk, BT, 0, stream>>>(positions, centroids, tables,
                                         W1, b1, W2, b2, out, n);
    }
}